// Round 5
// baseline (440.753 us; speedup 1.0000x reference)
//
#include <hip/hip_runtime.h>
#include <math.h>

#define NAG 6
#define CC  64
#define HH  128
#define WW  128
#define HWT 16384
#define BN_EPS 1e-5f

typedef unsigned int u32;
typedef __fp16 f16x2 __attribute__((ext_vector_type(2)));

#if defined(__has_builtin)
#if __has_builtin(__builtin_amdgcn_fdot2) && __has_builtin(__builtin_amdgcn_cvt_pkrtz)
#define USE_DOT2 1
#endif
#endif

// branch-free tanh-form gelu, exp2-folded
__device__ __forceinline__ float gelu_fast(float x) {
    float s = x * x;
    float m = fmaf(s, -0.10294535f, -2.30226045f);   // -(2*0.79788456*log2e)*(1+0.044715 s)
    float e = __builtin_amdgcn_exp2f(x * m);          // e^{-2a}
    return x * __builtin_amdgcn_rcpf(1.0f + e);       // x * sigmoid(2a)
}

// ---------------- init min/max slots ----------------
__global__ void k_init(u32* __restrict__ mm) {
    int t = threadIdx.x;
    if (t < NAG) mm[t] = 0x7F800000u;        // +inf (min slots)
    else if (t < 2 * NAG) mm[t] = 0u;        // 0    (max slots; h2 >= 0)
}

// ---------------- pack dw-conv weights: per (c,dy): 5 half2 pairs + 1 f32 tap ----------------
__global__ __launch_bounds__(256) void k_wpack(const float* __restrict__ dww,
                                               u32* __restrict__ pkw) {
    int t = blockIdx.x * 256 + threadIdx.x;
    if (t >= CC * 11) return;
    int c = t / 11, dy = t - c * 11;
    const float* w = dww + c * 121 + dy * 11;
    u32* o = pkw + (size_t)t * 6;
    #pragma unroll
    for (int p = 0; p < 5; ++p) {
        f16x2 h;
        h.x = (__fp16)w[2 * p];
        h.y = (__fp16)w[2 * p + 1];
        o[p] = __builtin_bit_cast(u32, h);
    }
    o[5] = __float_as_uint(w[10]);
}

// ---------------- confidence maps (pre-normalization) + per-agent min/max ----------------
__global__ __launch_bounds__(256) void k_conf(
    const float* __restrict__ raw,
    const float* __restrict__ w1, const float* __restrict__ b1,
    const float* __restrict__ gamma, const float* __restrict__ beta,
    const float* __restrict__ mean, const float* __restrict__ var,
    const float* __restrict__ w2, const float* __restrict__ b2,
    float* __restrict__ conf, u32* __restrict__ mm)
{
    const int n = blockIdx.y;
    const int p = blockIdx.x * 256 + threadIdx.x;
    const float* x = raw + (size_t)(n * CC) * HWT + p;

    float a[4] = {0.f, 0.f, 0.f, 0.f};
    #pragma unroll 8
    for (int c = 0; c < CC; ++c) {
        float v = x[c * HWT];
        a[0] = fmaf(w1[0 * CC + c], v, a[0]);
        a[1] = fmaf(w1[1 * CC + c], v, a[1]);
        a[2] = fmaf(w1[2 * CC + c], v, a[2]);
        a[3] = fmaf(w1[3 * CC + c], v, a[3]);
    }
    float h2 = b2[0];
    #pragma unroll
    for (int o = 0; o < 4; ++o) {
        float sc = gamma[o] * rsqrtf(var[o] + BN_EPS);
        float hb = (a[o] + b1[o] - mean[o]) * sc + beta[o];
        hb = fmaxf(hb, 0.f);
        h2 = fmaf(w2[o], hb, h2);
    }
    h2 = fmaxf(h2, 0.f);
    conf[n * HWT + p] = h2;

    float mn = h2, mx = h2;
    #pragma unroll
    for (int off = 32; off > 0; off >>= 1) {
        mn = fminf(mn, __shfl_xor(mn, off, 64));
        mx = fmaxf(mx, __shfl_xor(mx, off, 64));
    }
    __shared__ float smn[4], smx[4];
    int wid = threadIdx.x >> 6, lane = threadIdx.x & 63;
    if (lane == 0) { smn[wid] = mn; smx[wid] = mx; }
    __syncthreads();
    if (threadIdx.x == 0) {
        mn = fminf(fminf(smn[0], smn[1]), fminf(smn[2], smn[3]));
        mx = fmaxf(fmaxf(smx[0], smx[1]), fmaxf(smx[2], smx[3]));
        atomicMin(&mm[n], __float_as_uint(mn));
        atomicMax(&mm[n + NAG], __float_as_uint(mx));
    }
}

// ---------------- P = A1*raw, Q = A2*raw, W = (Vw*raw + vb) * conf_norm ----------------
__global__ __launch_bounds__(512) void k_pqv(
    const float* __restrict__ raw, const float* __restrict__ a1w,
    const float* __restrict__ vw, const float* __restrict__ vb,
    const float* __restrict__ conf, const u32* __restrict__ mm,
    float* __restrict__ P, float* __restrict__ Q, float* __restrict__ W)
{
    const int n = blockIdx.y;
    const int m = blockIdx.z;
    const int og = __builtin_amdgcn_readfirstlane(threadIdx.x >> 6);
    const int pg = threadIdx.x & 63;
    const int px = blockIdx.x * 256 + pg * 4;

    const float* wbase;
    int wstride;
    float* out;
    if (m == 0)      { wbase = a1w;      wstride = 2 * CC; out = P; }
    else if (m == 1) { wbase = a1w + CC; wstride = 2 * CC; out = Q; }
    else             { wbase = vw;       wstride = CC;     out = W; }

    const float* xb = raw + (size_t)(n * CC) * HWT + px;

    float acc[8][4];
    #pragma unroll
    for (int j = 0; j < 8; ++j)
        for (int q = 0; q < 4; ++q) acc[j][q] = 0.f;

    #pragma unroll 4
    for (int c = 0; c < CC; ++c) {
        float4 x = *(const float4*)(xb + (size_t)c * HWT);
        #pragma unroll
        for (int j = 0; j < 8; ++j) {
            float w = wbase[(og * 8 + j) * wstride + c];
            acc[j][0] = fmaf(w, x.x, acc[j][0]);
            acc[j][1] = fmaf(w, x.y, acc[j][1]);
            acc[j][2] = fmaf(w, x.z, acc[j][2]);
            acc[j][3] = fmaf(w, x.w, acc[j][3]);
        }
    }

    float4 cn = make_float4(1.f, 1.f, 1.f, 1.f);
    if (m == 2) {
        const float mn = __uint_as_float(mm[n]);
        const float mx = __uint_as_float(mm[n + NAG]);
        const float inv = 1.f / (mx - mn);
        float4 cv = *(const float4*)(conf + n * HWT + px);
        cn = make_float4((cv.x - mn) * inv, (cv.y - mn) * inv,
                         (cv.z - mn) * inv, (cv.w - mn) * inv);
    }

    #pragma unroll
    for (int j = 0; j < 8; ++j) {
        int o = og * 8 + j;
        float4 r;
        if (m == 2) {
            float b = vb[o];
            r = make_float4((acc[j][0] + b) * cn.x, (acc[j][1] + b) * cn.y,
                            (acc[j][2] + b) * cn.z, (acc[j][3] + b) * cn.w);
        } else {
            r = make_float4(acc[j][0], acc[j][1], acc[j][2], acc[j][3]);
        }
        *(float4*)(out + (size_t)(n * CC + o) * HWT + px) = r;
    }
}

// ---------------- main: S[i,c] = (sum_k dwconv11(gelu(P_i+Q_k+b)) * W_k) ----------------
#define TS 64            // output tile side
#define GP 76            // LDS tile pitch (floats)
#define GR 74            // LDS tile rows (64 + 2*5)
#define GN (GR * GP)     // 5624
#define NU 22            // ceil(GN / 256)

__global__ __launch_bounds__(256, 5) void k_main(
    const float* __restrict__ P, const float* __restrict__ Q,
    const float* __restrict__ W, const float* __restrict__ conf,
    const u32* __restrict__ mm,
    const float* __restrict__ a1b, const float* __restrict__ dww,
    const u32* __restrict__ pkw,
    const float* __restrict__ dwb, float* __restrict__ S)
{
    const int tile = blockIdx.x;              // 0..3
    const int c    = blockIdx.y;              // 0..63
    const int i    = blockIdx.z;              // 0..5
    const int y0 = (tile >> 1) * TS;
    const int x0 = (tile & 1) * TS;
    const int t  = threadIdx.x;
    const int r0  = (t >> 4) * 4;
    const int px0 = (t & 15) * 4;

    __shared__ float GT[GN];

    const float ba1 = a1b[c];
    const float bdw = dwb[c];
#if !USE_DOT2
    const float* wr = dww + c * 121;
#endif

    // preload halo'd P tile (+ a1 bias) into registers, remember global offsets
    float preg[NU];
    int   offs[NU];
    const float* Pc = P + (size_t)(i * CC + c) * HWT;
    #pragma unroll
    for (int u = 0; u < NU; ++u) {
        int idx = t + u * 256;
        int row = idx / GP, col = idx - row * GP;
        int gy = y0 + row - 5, gx = x0 + col - 5;
        bool inb = (idx < GN) && (col < GR) &&
                   (gy >= 0) && (gy < HH) && (gx >= 0) && (gx < WW);
        offs[u] = inb ? (gy * WW + gx) : -1;
        preg[u] = inb ? (Pc[gy * WW + gx] + ba1) : 0.f;
    }

    const int obase = (y0 + r0) * WW + x0 + px0;

    float sacc[4][4];
    #pragma unroll
    for (int j = 0; j < 4; ++j)
        for (int q = 0; q < 4; ++q) sacc[j][q] = 0.f;

    // prefetch Q for k=0
    float qreg[NU];
    {
        const float* Qc = Q + (size_t)(0 * CC + c) * HWT;
        #pragma unroll
        for (int u = 0; u < NU; ++u)
            qreg[u] = (offs[u] >= 0) ? Qc[offs[u]] : 0.f;
    }

    #pragma unroll 1
    for (int k = 0; k < NAG; ++k) {
        // ---- prefetch this k's W values early (consumed after the conv)
        const float* Wc = W + (size_t)(k * CC + c) * HWT;
        float4 wk[4];
        #pragma unroll
        for (int j = 0; j < 4; ++j)
            wk[j] = *(const float4*)(Wc + obase + j * WW);

        // ---- write phase: GT = gelu(P + Q + b)
        #pragma unroll
        for (int u = 0; u < NU - 1; ++u)
            GT[t + u * 256] = gelu_fast(preg[u] + qreg[u]);
        {
            int idx = t + (NU - 1) * 256;
            if (idx < GN) GT[idx] = gelu_fast(preg[NU - 1] + qreg[NU - 1]);
        }
        __syncthreads();

        // ---- prefetch next k's Q (latency hidden under the conv)
        if (k + 1 < NAG) {
            const float* Qc = Q + (size_t)((k + 1) * CC + c) * HWT;
            #pragma unroll
            for (int u = 0; u < NU; ++u)
                qreg[u] = (offs[u] >= 0) ? Qc[offs[u]] : 0.f;
        }

        // ---- 11x11 depthwise conv, 4x4 register blocking
        float cacc[4][4];
        #pragma unroll
        for (int j = 0; j < 4; ++j)
            for (int q = 0; q < 4; ++q) cacc[j][q] = 0.f;

        #pragma unroll
        for (int iy = 0; iy < 14; ++iy) {
            float wf[16];
            const float4* gp = (const float4*)&GT[(r0 + iy) * GP] + (t & 15);
            #pragma unroll
            for (int q = 0; q < 4; ++q) {
                float4 s = gp[q];
                wf[q * 4 + 0] = s.x; wf[q * 4 + 1] = s.y;
                wf[q * 4 + 2] = s.z; wf[q * 4 + 3] = s.w;
            }
#if USE_DOT2
            // pack 12 overlapping f16 pairs
            f16x2 pk[12];
            #pragma unroll
            for (int s = 0; s < 12; ++s)
                pk[s] = __builtin_amdgcn_cvt_pkrtz(wf[s], wf[s + 1]);
#endif
            #pragma unroll
            for (int j = 0; j < 4; ++j) {
                int dy = iy - j;
                if (dy >= 0 && dy <= 10) {
#if USE_DOT2
                    const u32* wrow = pkw + (size_t)(c * 11 + dy) * 6;  // uniform -> s_load
                    f16x2 w0 = __builtin_bit_cast(f16x2, wrow[0]);
                    f16x2 w1 = __builtin_bit_cast(f16x2, wrow[1]);
                    f16x2 w2 = __builtin_bit_cast(f16x2, wrow[2]);
                    f16x2 w3 = __builtin_bit_cast(f16x2, wrow[3]);
                    f16x2 w4 = __builtin_bit_cast(f16x2, wrow[4]);
                    float w10 = __uint_as_float(wrow[5]);
                    #pragma unroll
                    for (int q = 0; q < 4; ++q) {
                        float acc = cacc[j][q];
                        acc = __builtin_amdgcn_fdot2(w0, pk[q + 0], acc, false);
                        acc = __builtin_amdgcn_fdot2(w1, pk[q + 2], acc, false);
                        acc = __builtin_amdgcn_fdot2(w2, pk[q + 4], acc, false);
                        acc = __builtin_amdgcn_fdot2(w3, pk[q + 6], acc, false);
                        acc = __builtin_amdgcn_fdot2(w4, pk[q + 8], acc, false);
                        cacc[j][q] = fmaf(w10, wf[q + 10], acc);
                    }
#else
                    #pragma unroll
                    for (int dx = 0; dx < 11; ++dx) {
                        float cw = wr[dy * 11 + dx];
                        cacc[j][0] = fmaf(cw, wf[dx + 0], cacc[j][0]);
                        cacc[j][1] = fmaf(cw, wf[dx + 1], cacc[j][1]);
                        cacc[j][2] = fmaf(cw, wf[dx + 2], cacc[j][2]);
                        cacc[j][3] = fmaf(cw, wf[dx + 3], cacc[j][3]);
                    }
#endif
                }
            }
        }
        __syncthreads();

        // ---- accumulate with W_k
        #pragma unroll
        for (int j = 0; j < 4; ++j) {
            sacc[j][0] = fmaf(cacc[j][0] + bdw, wk[j].x, sacc[j][0]);
            sacc[j][1] = fmaf(cacc[j][1] + bdw, wk[j].y, sacc[j][1]);
            sacc[j][2] = fmaf(cacc[j][2] + bdw, wk[j].z, sacc[j][2]);
            sacc[j][3] = fmaf(cacc[j][3] + bdw, wk[j].w, sacc[j][3]);
        }
    }

    // ---- epilogue: multiply by (1 - conf_norm_i), store
    const float mn = __uint_as_float(mm[i]);
    const float mx = __uint_as_float(mm[i + NAG]);
    const float inv = 1.f / (mx - mn);
    const float* cfi = conf + i * HWT;
    float* Sc = S + (size_t)(i * CC + c) * HWT;
    #pragma unroll
    for (int j = 0; j < 4; ++j) {
        float4 cv = *(const float4*)(cfi + obase + j * WW);
        float4 r;
        r.x = sacc[j][0] * (1.f - (cv.x - mn) * inv);
        r.y = sacc[j][1] * (1.f - (cv.y - mn) * inv);
        r.z = sacc[j][2] * (1.f - (cv.z - mn) * inv);
        r.w = sacc[j][3] * (1.f - (cv.w - mn) * inv);
        *(float4*)(Sc + obase + j * WW) = r;
    }
}

// ---------------- epilogue: out = raw + projW * S + 6*pb (S aliases out) ----------------
__global__ __launch_bounds__(512) void k_out(
    float* so,
    const float* __restrict__ raw,
    const float* __restrict__ pw, const float* __restrict__ pb)
{
    const int n = blockIdx.y;
    const int og = __builtin_amdgcn_readfirstlane(threadIdx.x >> 6);
    const int pg = threadIdx.x & 63;
    const int px = blockIdx.x * 256 + pg * 4;

    const float* xb = so + (size_t)(n * CC) * HWT + px;

    float acc[8][4];
    #pragma unroll
    for (int j = 0; j < 8; ++j)
        for (int q = 0; q < 4; ++q) acc[j][q] = 0.f;

    #pragma unroll 4
    for (int c = 0; c < CC; ++c) {
        float4 x = *(const float4*)(xb + (size_t)c * HWT);
        #pragma unroll
        for (int j = 0; j < 8; ++j) {
            float w = pw[(og * 8 + j) * CC + c];
            acc[j][0] = fmaf(w, x.x, acc[j][0]);
            acc[j][1] = fmaf(w, x.y, acc[j][1]);
            acc[j][2] = fmaf(w, x.z, acc[j][2]);
            acc[j][3] = fmaf(w, x.w, acc[j][3]);
        }
    }

    __syncthreads();

    #pragma unroll
    for (int j = 0; j < 8; ++j) {
        int o = og * 8 + j;
        float bias = (float)NAG * pb[o];
        float4 r = *(const float4*)(raw + (size_t)(n * CC + o) * HWT + px);
        float4 w = make_float4(r.x + acc[j][0] + bias, r.y + acc[j][1] + bias,
                               r.z + acc[j][2] + bias, r.w + acc[j][3] + bias);
        *(float4*)(so + (size_t)(n * CC + o) * HWT + px) = w;
    }
}

extern "C" void kernel_launch(void* const* d_in, const int* in_sizes, int n_in,
                              void* d_out, int out_size, void* d_ws, size_t ws_size,
                              hipStream_t stream)
{
    (void)in_sizes; (void)n_in; (void)out_size; (void)ws_size;

    const float* raw   = (const float*)d_in[0];
    const float* pw_w1 = (const float*)d_in[1];
    const float* pw_b1 = (const float*)d_in[2];
    const float* bng   = (const float*)d_in[3];
    const float* bnb   = (const float*)d_in[4];
    const float* bnm   = (const float*)d_in[5];
    const float* bnv   = (const float*)d_in[6];
    const float* pw_w2 = (const float*)d_in[7];
    const float* pw_b2 = (const float*)d_in[8];
    const float* a1w   = (const float*)d_in[9];
    const float* a1b   = (const float*)d_in[10];
    const float* dww   = (const float*)d_in[11];
    const float* dwb   = (const float*)d_in[12];
    const float* vw    = (const float*)d_in[13];
    const float* vb    = (const float*)d_in[14];
    const float* pjw   = (const float*)d_in[15];
    const float* pjb   = (const float*)d_in[16];

    float* ws   = (float*)d_ws;
    float* conf = ws;                                  // 6*16384
    u32*   mm   = (u32*)(ws + NAG * HWT);              // 12 (padded to 16)
    float* P    = ws + NAG * HWT + 16;                 // 6*64*16384
    float* Q    = P + (size_t)NAG * CC * HWT;
    float* W    = Q + (size_t)NAG * CC * HWT;
    u32*   pkw  = (u32*)(W + (size_t)NAG * CC * HWT);  // 64*11*6 dwords
    float* S    = (float*)d_out;                       // S aliases output

    k_init<<<dim3(1), dim3(64), 0, stream>>>(mm);
    k_wpack<<<dim3(3), dim3(256), 0, stream>>>(dww, pkw);
    k_conf<<<dim3(HWT / 256, NAG), dim3(256), 0, stream>>>(raw, pw_w1, pw_b1, bng, bnb,
                                                           bnm, bnv, pw_w2, pw_b2, conf, mm);
    k_pqv<<<dim3(HWT / 256, NAG, 3), dim3(512), 0, stream>>>(raw, a1w, vw, vb, conf, mm, P, Q, W);
    k_main<<<dim3(4, CC, NAG), dim3(256), 0, stream>>>(P, Q, W, conf, mm, a1b, dww, pkw, dwb, S);
    k_out<<<dim3(HWT / 256, NAG), dim3(512), 0, stream>>>(S, raw, pjw, pjb);
}

// Round 6
// 229.320 us; speedup vs baseline: 1.9220x; 1.9220x over previous
//
#include <hip/hip_runtime.h>
#include <math.h>

#define NAG 6
#define CC  64
#define HH  128
#define WW  128
#define HWT 16384
#define BN_EPS 1e-5f

typedef unsigned int u32;
typedef __fp16 f16x2 __attribute__((ext_vector_type(2)));

#if defined(__has_builtin)
#if __has_builtin(__builtin_amdgcn_fdot2) && __has_builtin(__builtin_amdgcn_cvt_pkrtz)
#define USE_DOT2 1
#endif
#endif

// branch-free tanh-form gelu, exp2-folded
__device__ __forceinline__ float gelu_fast(float x) {
    float s = x * x;
    float m = fmaf(s, -0.10294535f, -2.30226045f);   // -(2*0.79788456*log2e)*(1+0.044715 s)
    float e = __builtin_amdgcn_exp2f(x * m);          // e^{-2a}
    return x * __builtin_amdgcn_rcpf(1.0f + e);       // x * sigmoid(2a)
}

// ---------------- init min/max slots ----------------
__global__ void k_init(u32* __restrict__ mm) {
    int t = threadIdx.x;
    if (t < NAG) mm[t] = 0x7F800000u;        // +inf (min slots)
    else if (t < 2 * NAG) mm[t] = 0u;        // 0    (max slots; h2 >= 0)
}

// ---------------- pack dw-conv weights: per (c,dy): 5 half2 pairs + 1 f32 tap ----------------
__global__ __launch_bounds__(256) void k_wpack(const float* __restrict__ dww,
                                               u32* __restrict__ pkw) {
    int t = blockIdx.x * 256 + threadIdx.x;
    if (t >= CC * 11) return;
    int c = t / 11, dy = t - c * 11;
    const float* w = dww + c * 121 + dy * 11;
    u32* o = pkw + (size_t)t * 6;
    #pragma unroll
    for (int p = 0; p < 5; ++p) {
        f16x2 h;
        h.x = (__fp16)w[2 * p];
        h.y = (__fp16)w[2 * p + 1];
        o[p] = __builtin_bit_cast(u32, h);
    }
    o[5] = __float_as_uint(w[10]);
}

// ---------------- confidence maps (pre-normalization) + per-agent min/max ----------------
__global__ __launch_bounds__(256) void k_conf(
    const float* __restrict__ raw,
    const float* __restrict__ w1, const float* __restrict__ b1,
    const float* __restrict__ gamma, const float* __restrict__ beta,
    const float* __restrict__ mean, const float* __restrict__ var,
    const float* __restrict__ w2, const float* __restrict__ b2,
    float* __restrict__ conf, u32* __restrict__ mm)
{
    const int n = blockIdx.y;
    const int p = blockIdx.x * 256 + threadIdx.x;
    const float* x = raw + (size_t)(n * CC) * HWT + p;

    float a[4] = {0.f, 0.f, 0.f, 0.f};
    #pragma unroll 8
    for (int c = 0; c < CC; ++c) {
        float v = x[c * HWT];
        a[0] = fmaf(w1[0 * CC + c], v, a[0]);
        a[1] = fmaf(w1[1 * CC + c], v, a[1]);
        a[2] = fmaf(w1[2 * CC + c], v, a[2]);
        a[3] = fmaf(w1[3 * CC + c], v, a[3]);
    }
    float h2 = b2[0];
    #pragma unroll
    for (int o = 0; o < 4; ++o) {
        float sc = gamma[o] * rsqrtf(var[o] + BN_EPS);
        float hb = (a[o] + b1[o] - mean[o]) * sc + beta[o];
        hb = fmaxf(hb, 0.f);
        h2 = fmaf(w2[o], hb, h2);
    }
    h2 = fmaxf(h2, 0.f);
    conf[n * HWT + p] = h2;

    float mn = h2, mx = h2;
    #pragma unroll
    for (int off = 32; off > 0; off >>= 1) {
        mn = fminf(mn, __shfl_xor(mn, off, 64));
        mx = fmaxf(mx, __shfl_xor(mx, off, 64));
    }
    __shared__ float smn[4], smx[4];
    int wid = threadIdx.x >> 6, lane = threadIdx.x & 63;
    if (lane == 0) { smn[wid] = mn; smx[wid] = mx; }
    __syncthreads();
    if (threadIdx.x == 0) {
        mn = fminf(fminf(smn[0], smn[1]), fminf(smn[2], smn[3]));
        mx = fmaxf(fmaxf(smx[0], smx[1]), fmaxf(smx[2], smx[3]));
        atomicMin(&mm[n], __float_as_uint(mn));
        atomicMax(&mm[n + NAG], __float_as_uint(mx));
    }
}

// ---------------- P = A1*raw, Q = A2*raw, W = (Vw*raw + vb) * conf_norm ----------------
__global__ __launch_bounds__(512) void k_pqv(
    const float* __restrict__ raw, const float* __restrict__ a1w,
    const float* __restrict__ vw, const float* __restrict__ vb,
    const float* __restrict__ conf, const u32* __restrict__ mm,
    float* __restrict__ P, float* __restrict__ Q, float* __restrict__ W)
{
    const int n = blockIdx.y;
    const int m = blockIdx.z;
    const int og = __builtin_amdgcn_readfirstlane(threadIdx.x >> 6);
    const int pg = threadIdx.x & 63;
    const int px = blockIdx.x * 256 + pg * 4;

    const float* wbase;
    int wstride;
    float* out;
    if (m == 0)      { wbase = a1w;      wstride = 2 * CC; out = P; }
    else if (m == 1) { wbase = a1w + CC; wstride = 2 * CC; out = Q; }
    else             { wbase = vw;       wstride = CC;     out = W; }

    const float* xb = raw + (size_t)(n * CC) * HWT + px;

    float acc[8][4];
    #pragma unroll
    for (int j = 0; j < 8; ++j)
        for (int q = 0; q < 4; ++q) acc[j][q] = 0.f;

    #pragma unroll 4
    for (int c = 0; c < CC; ++c) {
        float4 x = *(const float4*)(xb + (size_t)c * HWT);
        #pragma unroll
        for (int j = 0; j < 8; ++j) {
            float w = wbase[(og * 8 + j) * wstride + c];
            acc[j][0] = fmaf(w, x.x, acc[j][0]);
            acc[j][1] = fmaf(w, x.y, acc[j][1]);
            acc[j][2] = fmaf(w, x.z, acc[j][2]);
            acc[j][3] = fmaf(w, x.w, acc[j][3]);
        }
    }

    float4 cn = make_float4(1.f, 1.f, 1.f, 1.f);
    if (m == 2) {
        const float mn = __uint_as_float(mm[n]);
        const float mx = __uint_as_float(mm[n + NAG]);
        const float inv = 1.f / (mx - mn);
        float4 cv = *(const float4*)(conf + n * HWT + px);
        cn = make_float4((cv.x - mn) * inv, (cv.y - mn) * inv,
                         (cv.z - mn) * inv, (cv.w - mn) * inv);
    }

    #pragma unroll
    for (int j = 0; j < 8; ++j) {
        int o = og * 8 + j;
        float4 r;
        if (m == 2) {
            float b = vb[o];
            r = make_float4((acc[j][0] + b) * cn.x, (acc[j][1] + b) * cn.y,
                            (acc[j][2] + b) * cn.z, (acc[j][3] + b) * cn.w);
        } else {
            r = make_float4(acc[j][0], acc[j][1], acc[j][2], acc[j][3]);
        }
        *(float4*)(out + (size_t)(n * CC + o) * HWT + px) = r;
    }
}

// ---------------- main: S[i,c] = (sum_k dwconv11(gelu(P_i+Q_k+b)) * W_k) ----------------
#define TS 64            // output tile side
#define GP 76            // LDS tile pitch (floats)
#define GR 74            // LDS tile rows (64 + 2*5)
#define GN (GR * GP)     // 5624
#define NU 22            // ceil(GN / 256)

__global__ __launch_bounds__(256, 3) void k_main(
    const float* __restrict__ P, const float* __restrict__ Q,
    const float* __restrict__ W, const float* __restrict__ conf,
    const u32* __restrict__ mm,
    const float* __restrict__ a1b, const float* __restrict__ dww,
    const u32* __restrict__ pkw,
    const float* __restrict__ dwb, float* __restrict__ S)
{
    const int tile = blockIdx.x;              // 0..3
    const int c    = blockIdx.y;              // 0..63
    const int i    = blockIdx.z;              // 0..5
    const int y0 = (tile >> 1) * TS;
    const int x0 = (tile & 1) * TS;
    const int t  = threadIdx.x;
    const int r0  = (t >> 4) * 4;
    const int px0 = (t & 15) * 4;

    __shared__ float GT[GN];

    const float ba1 = a1b[c];
    const float bdw = dwb[c];
#if !USE_DOT2
    const float* wr = dww + c * 121;
#endif

    // preload halo'd P tile (+ a1 bias) into registers, remember global offsets
    float preg[NU];
    int   offs[NU];
    const float* Pc = P + (size_t)(i * CC + c) * HWT;
    #pragma unroll
    for (int u = 0; u < NU; ++u) {
        int idx = t + u * 256;
        int row = idx / GP, col = idx - row * GP;
        int gy = y0 + row - 5, gx = x0 + col - 5;
        bool inb = (idx < GN) && (col < GR) &&
                   (gy >= 0) && (gy < HH) && (gx >= 0) && (gx < WW);
        offs[u] = inb ? (gy * WW + gx) : -1;
        preg[u] = inb ? (Pc[gy * WW + gx] + ba1) : 0.f;
    }

    const int obase = (y0 + r0) * WW + x0 + px0;

    float sacc[4][4];
    #pragma unroll
    for (int j = 0; j < 4; ++j)
        for (int q = 0; q < 4; ++q) sacc[j][q] = 0.f;

    // prefetch Q for k=0
    float qreg[NU];
    {
        const float* Qc = Q + (size_t)(0 * CC + c) * HWT;
        #pragma unroll
        for (int u = 0; u < NU; ++u)
            qreg[u] = (offs[u] >= 0) ? Qc[offs[u]] : 0.f;
    }

    #pragma unroll 1
    for (int k = 0; k < NAG; ++k) {
        // ---- prefetch this k's W values early (consumed after the conv)
        const float* Wc = W + (size_t)(k * CC + c) * HWT;
        float4 wk[4];
        #pragma unroll
        for (int j = 0; j < 4; ++j)
            wk[j] = *(const float4*)(Wc + obase + j * WW);

        // ---- write phase: GT = gelu(P + Q + b)
        #pragma unroll
        for (int u = 0; u < NU - 1; ++u)
            GT[t + u * 256] = gelu_fast(preg[u] + qreg[u]);
        {
            int idx = t + (NU - 1) * 256;
            if (idx < GN) GT[idx] = gelu_fast(preg[NU - 1] + qreg[NU - 1]);
        }
        __syncthreads();

        // ---- prefetch next k's Q (latency hidden under the conv)
        if (k + 1 < NAG) {
            const float* Qc = Q + (size_t)((k + 1) * CC + c) * HWT;
            #pragma unroll
            for (int u = 0; u < NU; ++u)
                qreg[u] = (offs[u] >= 0) ? Qc[offs[u]] : 0.f;
        }

        // ---- 11x11 depthwise conv, 4x4 register blocking
        float cacc[4][4];
        #pragma unroll
        for (int j = 0; j < 4; ++j)
            for (int q = 0; q < 4; ++q) cacc[j][q] = 0.f;

        #pragma unroll
        for (int iy = 0; iy < 14; ++iy) {
            float wf[16];
            const float4* gp = (const float4*)&GT[(r0 + iy) * GP] + (t & 15);
            #pragma unroll
            for (int q = 0; q < 4; ++q) {
                float4 s = gp[q];
                wf[q * 4 + 0] = s.x; wf[q * 4 + 1] = s.y;
                wf[q * 4 + 2] = s.z; wf[q * 4 + 3] = s.w;
            }
#if USE_DOT2
            // pack 12 overlapping f16 pairs
            f16x2 pk[12];
            #pragma unroll
            for (int s = 0; s < 12; ++s)
                pk[s] = __builtin_amdgcn_cvt_pkrtz(wf[s], wf[s + 1]);
#endif
            #pragma unroll
            for (int j = 0; j < 4; ++j) {
                int dy = iy - j;
                if (dy >= 0 && dy <= 10) {
#if USE_DOT2
                    const u32* wrow = pkw + (size_t)(c * 11 + dy) * 6;  // uniform -> s_load
                    f16x2 w0 = __builtin_bit_cast(f16x2, wrow[0]);
                    f16x2 w1 = __builtin_bit_cast(f16x2, wrow[1]);
                    f16x2 w2 = __builtin_bit_cast(f16x2, wrow[2]);
                    f16x2 w3 = __builtin_bit_cast(f16x2, wrow[3]);
                    f16x2 w4 = __builtin_bit_cast(f16x2, wrow[4]);
                    float w10 = __uint_as_float(wrow[5]);
                    #pragma unroll
                    for (int q = 0; q < 4; ++q) {
                        float acc = cacc[j][q];
                        acc = __builtin_amdgcn_fdot2(w0, pk[q + 0], acc, false);
                        acc = __builtin_amdgcn_fdot2(w1, pk[q + 2], acc, false);
                        acc = __builtin_amdgcn_fdot2(w2, pk[q + 4], acc, false);
                        acc = __builtin_amdgcn_fdot2(w3, pk[q + 6], acc, false);
                        acc = __builtin_amdgcn_fdot2(w4, pk[q + 8], acc, false);
                        cacc[j][q] = fmaf(w10, wf[q + 10], acc);
                    }
#else
                    #pragma unroll
                    for (int dx = 0; dx < 11; ++dx) {
                        float cw = wr[dy * 11 + dx];
                        cacc[j][0] = fmaf(cw, wf[dx + 0], cacc[j][0]);
                        cacc[j][1] = fmaf(cw, wf[dx + 1], cacc[j][1]);
                        cacc[j][2] = fmaf(cw, wf[dx + 2], cacc[j][2]);
                        cacc[j][3] = fmaf(cw, wf[dx + 3], cacc[j][3]);
                    }
#endif
                }
            }
        }
        __syncthreads();

        // ---- accumulate with W_k
        #pragma unroll
        for (int j = 0; j < 4; ++j) {
            sacc[j][0] = fmaf(cacc[j][0] + bdw, wk[j].x, sacc[j][0]);
            sacc[j][1] = fmaf(cacc[j][1] + bdw, wk[j].y, sacc[j][1]);
            sacc[j][2] = fmaf(cacc[j][2] + bdw, wk[j].z, sacc[j][2]);
            sacc[j][3] = fmaf(cacc[j][3] + bdw, wk[j].w, sacc[j][3]);
        }
    }

    // ---- epilogue: multiply by (1 - conf_norm_i), store
    const float mn = __uint_as_float(mm[i]);
    const float mx = __uint_as_float(mm[i + NAG]);
    const float inv = 1.f / (mx - mn);
    const float* cfi = conf + i * HWT;
    float* Sc = S + (size_t)(i * CC + c) * HWT;
    #pragma unroll
    for (int j = 0; j < 4; ++j) {
        float4 cv = *(const float4*)(cfi + obase + j * WW);
        float4 r;
        r.x = sacc[j][0] * (1.f - (cv.x - mn) * inv);
        r.y = sacc[j][1] * (1.f - (cv.y - mn) * inv);
        r.z = sacc[j][2] * (1.f - (cv.z - mn) * inv);
        r.w = sacc[j][3] * (1.f - (cv.w - mn) * inv);
        *(float4*)(Sc + obase + j * WW) = r;
    }
}

// ---------------- epilogue: out = raw + projW * S + 6*pb (S aliases out) ----------------
__global__ __launch_bounds__(512) void k_out(
    float* so,
    const float* __restrict__ raw,
    const float* __restrict__ pw, const float* __restrict__ pb)
{
    const int n = blockIdx.y;
    const int og = __builtin_amdgcn_readfirstlane(threadIdx.x >> 6);
    const int pg = threadIdx.x & 63;
    const int px = blockIdx.x * 256 + pg * 4;

    const float* xb = so + (size_t)(n * CC) * HWT + px;

    float acc[8][4];
    #pragma unroll
    for (int j = 0; j < 8; ++j)
        for (int q = 0; q < 4; ++q) acc[j][q] = 0.f;

    #pragma unroll 4
    for (int c = 0; c < CC; ++c) {
        float4 x = *(const float4*)(xb + (size_t)c * HWT);
        #pragma unroll
        for (int j = 0; j < 8; ++j) {
            float w = pw[(og * 8 + j) * CC + c];
            acc[j][0] = fmaf(w, x.x, acc[j][0]);
            acc[j][1] = fmaf(w, x.y, acc[j][1]);
            acc[j][2] = fmaf(w, x.z, acc[j][2]);
            acc[j][3] = fmaf(w, x.w, acc[j][3]);
        }
    }

    __syncthreads();

    #pragma unroll
    for (int j = 0; j < 8; ++j) {
        int o = og * 8 + j;
        float bias = (float)NAG * pb[o];
        float4 r = *(const float4*)(raw + (size_t)(n * CC + o) * HWT + px);
        float4 w = make_float4(r.x + acc[j][0] + bias, r.y + acc[j][1] + bias,
                               r.z + acc[j][2] + bias, r.w + acc[j][3] + bias);
        *(float4*)(so + (size_t)(n * CC + o) * HWT + px) = w;
    }
}

extern "C" void kernel_launch(void* const* d_in, const int* in_sizes, int n_in,
                              void* d_out, int out_size, void* d_ws, size_t ws_size,
                              hipStream_t stream)
{
    (void)in_sizes; (void)n_in; (void)out_size; (void)ws_size;

    const float* raw   = (const float*)d_in[0];
    const float* pw_w1 = (const float*)d_in[1];
    const float* pw_b1 = (const float*)d_in[2];
    const float* bng   = (const float*)d_in[3];
    const float* bnb   = (const float*)d_in[4];
    const float* bnm   = (const float*)d_in[5];
    const float* bnv   = (const float*)d_in[6];
    const float* pw_w2 = (const float*)d_in[7];
    const float* pw_b2 = (const float*)d_in[8];
    const float* a1w   = (const float*)d_in[9];
    const float* a1b   = (const float*)d_in[10];
    const float* dww   = (const float*)d_in[11];
    const float* dwb   = (const float*)d_in[12];
    const float* vw    = (const float*)d_in[13];
    const float* vb    = (const float*)d_in[14];
    const float* pjw   = (const float*)d_in[15];
    const float* pjb   = (const float*)d_in[16];

    float* ws   = (float*)d_ws;
    float* conf = ws;                                  // 6*16384
    u32*   mm   = (u32*)(ws + NAG * HWT);              // 12 (padded to 16)
    float* P    = ws + NAG * HWT + 16;                 // 6*64*16384
    float* Q    = P + (size_t)NAG * CC * HWT;
    float* W    = Q + (size_t)NAG * CC * HWT;
    u32*   pkw  = (u32*)(W + (size_t)NAG * CC * HWT);  // 64*11*6 dwords
    float* S    = (float*)d_out;                       // S aliases output

    k_init<<<dim3(1), dim3(64), 0, stream>>>(mm);
    k_wpack<<<dim3(3), dim3(256), 0, stream>>>(dww, pkw);
    k_conf<<<dim3(HWT / 256, NAG), dim3(256), 0, stream>>>(raw, pw_w1, pw_b1, bng, bnb,
                                                           bnm, bnv, pw_w2, pw_b2, conf, mm);
    k_pqv<<<dim3(HWT / 256, NAG, 3), dim3(512), 0, stream>>>(raw, a1w, vw, vb, conf, mm, P, Q, W);
    k_main<<<dim3(4, CC, NAG), dim3(256), 0, stream>>>(P, Q, W, conf, mm, a1b, dww, pkw, dwb, S);
    k_out<<<dim3(HWT / 256, NAG), dim3(512), 0, stream>>>(S, raw, pjw, pjb);
}

// Round 7
// 135.398 us; speedup vs baseline: 3.2552x; 1.6937x over previous
//
#include <hip/hip_runtime.h>
#include <math.h>

#define NAG 6
#define CC  64
#define HH  128
#define WW  128
#define HWT 16384
#define HWP 8192             // packed f16 pairs per (agent,channel) plane
#define BN_EPS 1e-5f

typedef unsigned int u32;
typedef __fp16 f16x2v __attribute__((ext_vector_type(2)));
typedef __fp16 f16x8  __attribute__((ext_vector_type(8)));
typedef float  f32x4  __attribute__((ext_vector_type(4)));

// branch-free tanh-form gelu, exp2-folded
__device__ __forceinline__ float gelu_fast(float x) {
    float s = x * x;
    float m = fmaf(s, -0.10294535f, -2.30226045f);   // -(2*0.79788456*log2e)*(1+0.044715 s)
    float e = __builtin_amdgcn_exp2f(x * m);          // e^{-2a}
    return x * __builtin_amdgcn_rcpf(1.0f + e);       // x * sigmoid(2a)
}

// ---------------- init min/max slots ----------------
__global__ void k_init(u32* __restrict__ mm) {
    int t = threadIdx.x;
    if (t < NAG) mm[t] = 0x7F800000u;        // +inf (min slots)
    else if (t < 2 * NAG) mm[t] = 0u;        // 0    (max slots; h2 >= 0)
}

// ---------------- confidence maps (pre-normalization) + per-agent min/max ----------------
__global__ __launch_bounds__(256) void k_conf(
    const float* __restrict__ raw,
    const float* __restrict__ w1, const float* __restrict__ b1,
    const float* __restrict__ gamma, const float* __restrict__ beta,
    const float* __restrict__ mean, const float* __restrict__ var,
    const float* __restrict__ w2, const float* __restrict__ b2,
    float* __restrict__ conf, u32* __restrict__ mm)
{
    const int n = blockIdx.y;
    const int p = blockIdx.x * 256 + threadIdx.x;
    const float* x = raw + (size_t)(n * CC) * HWT + p;

    float a[4] = {0.f, 0.f, 0.f, 0.f};
    #pragma unroll 8
    for (int c = 0; c < CC; ++c) {
        float v = x[c * HWT];
        a[0] = fmaf(w1[0 * CC + c], v, a[0]);
        a[1] = fmaf(w1[1 * CC + c], v, a[1]);
        a[2] = fmaf(w1[2 * CC + c], v, a[2]);
        a[3] = fmaf(w1[3 * CC + c], v, a[3]);
    }
    float h2 = b2[0];
    #pragma unroll
    for (int o = 0; o < 4; ++o) {
        float sc = gamma[o] * rsqrtf(var[o] + BN_EPS);
        float hb = (a[o] + b1[o] - mean[o]) * sc + beta[o];
        hb = fmaxf(hb, 0.f);
        h2 = fmaf(w2[o], hb, h2);
    }
    h2 = fmaxf(h2, 0.f);
    conf[n * HWT + p] = h2;

    float mn = h2, mx = h2;
    #pragma unroll
    for (int off = 32; off > 0; off >>= 1) {
        mn = fminf(mn, __shfl_xor(mn, off, 64));
        mx = fmaxf(mx, __shfl_xor(mx, off, 64));
    }
    __shared__ float smn[4], smx[4];
    int wid = threadIdx.x >> 6, lane = threadIdx.x & 63;
    if (lane == 0) { smn[wid] = mn; smx[wid] = mx; }
    __syncthreads();
    if (threadIdx.x == 0) {
        mn = fminf(fminf(smn[0], smn[1]), fminf(smn[2], smn[3]));
        mx = fmaxf(fmaxf(smx[0], smx[1]), fmaxf(smx[2], smx[3]));
        atomicMin(&mm[n], __float_as_uint(mn));
        atomicMax(&mm[n + NAG], __float_as_uint(mx));
    }
}

// ---------------- P = A1*raw (f16 pairs), Q = A2*raw (f16 pairs), W = (Vw*raw+vb)*conf_norm (f32) ----------------
__global__ __launch_bounds__(512) void k_pqv(
    const float* __restrict__ raw, const float* __restrict__ a1w,
    const float* __restrict__ vw, const float* __restrict__ vb,
    const float* __restrict__ conf, const u32* __restrict__ mm,
    u32* __restrict__ Ph, u32* __restrict__ Qh, float* __restrict__ W)
{
    const int n = blockIdx.y;
    const int m = blockIdx.z;
    const int og = __builtin_amdgcn_readfirstlane(threadIdx.x >> 6);
    const int pg = threadIdx.x & 63;
    const int px = blockIdx.x * 256 + pg * 4;

    const float* wbase;
    int wstride;
    if (m == 0)      { wbase = a1w;      wstride = 2 * CC; }
    else if (m == 1) { wbase = a1w + CC; wstride = 2 * CC; }
    else             { wbase = vw;       wstride = CC;     }

    const float* xb = raw + (size_t)(n * CC) * HWT + px;

    float acc[8][4];
    #pragma unroll
    for (int j = 0; j < 8; ++j)
        for (int q = 0; q < 4; ++q) acc[j][q] = 0.f;

    #pragma unroll 4
    for (int c = 0; c < CC; ++c) {
        float4 x = *(const float4*)(xb + (size_t)c * HWT);
        #pragma unroll
        for (int j = 0; j < 8; ++j) {
            float w = wbase[(og * 8 + j) * wstride + c];
            acc[j][0] = fmaf(w, x.x, acc[j][0]);
            acc[j][1] = fmaf(w, x.y, acc[j][1]);
            acc[j][2] = fmaf(w, x.z, acc[j][2]);
            acc[j][3] = fmaf(w, x.w, acc[j][3]);
        }
    }

    if (m == 2) {
        const float mn = __uint_as_float(mm[n]);
        const float mx = __uint_as_float(mm[n + NAG]);
        const float inv = 1.f / (mx - mn);
        float4 cv = *(const float4*)(conf + n * HWT + px);
        float4 cn = make_float4((cv.x - mn) * inv, (cv.y - mn) * inv,
                                (cv.z - mn) * inv, (cv.w - mn) * inv);
        #pragma unroll
        for (int j = 0; j < 8; ++j) {
            int o = og * 8 + j;
            float b = vb[o];
            float4 r = make_float4((acc[j][0] + b) * cn.x, (acc[j][1] + b) * cn.y,
                                   (acc[j][2] + b) * cn.z, (acc[j][3] + b) * cn.w);
            *(float4*)(W + (size_t)(n * CC + o) * HWT + px) = r;
        }
    } else {
        u32* outh = (m == 0) ? Ph : Qh;
        #pragma unroll
        for (int j = 0; j < 8; ++j) {
            int o = og * 8 + j;
            f16x2v h0 = __builtin_amdgcn_cvt_pkrtz(acc[j][0], acc[j][1]);
            f16x2v h1 = __builtin_amdgcn_cvt_pkrtz(acc[j][2], acc[j][3]);
            uint2 v = make_uint2(__builtin_bit_cast(u32, h0), __builtin_bit_cast(u32, h1));
            *(uint2*)(outh + (size_t)(n * CC + o) * HWP + (px >> 1)) = v;
        }
    }
}

// ---------------- main: S[i,c] = sum_k dwconv11(gelu(P_i+Q_k+b)) * W_k, conv via MFMA ----------------
// GT: f16, 74 rows x 88-half pitch; GT col 0 = image x0-8, row 0 = image y0-5.
// Per wave (ty): 16 output rows, 4 tiles of 16 cols. Per (tile,dy): 1 ds_read_b128 + 1 MFMA 16x16x32.
#define GPITCH 88
#define GROWS  74
#define GDW    (GROWS * GPITCH / 2)   // 3256 dwords
#define NU2    13

__global__ __launch_bounds__(256, 3) void k_main(
    const u32* __restrict__ Ph, const u32* __restrict__ Qh,
    const float* __restrict__ W, const float* __restrict__ conf,
    const u32* __restrict__ mm,
    const float* __restrict__ a1b, const float* __restrict__ dww,
    const float* __restrict__ dwb, float* __restrict__ S)
{
    const int tile = blockIdx.x;              // 0..3 image quadrant
    const int c    = blockIdx.y;              // 0..63
    const int i    = blockIdx.z;              // 0..5
    const int y0 = (tile >> 1) * 64;
    const int x0 = (tile & 1) * 64;
    const int t    = threadIdx.x;
    const int lane = t & 63;
    const int ty   = t >> 6;                  // wave id = output row-tile
    const int lm   = lane & 15;
    const int kg   = lane >> 4;               // 0..3
    const int kg8  = kg * 8;

    __shared__ __align__(16) u32 GT32[GDW];
    const __fp16* GTh = (const __fp16*)GT32;

    const float bdw = dwb[c];
    const float ba1 = a1b[c];

    // ---- A fragments: Toeplitz band A[m][k] = w[dy][k-m-3], lane: m=lm, k=kg8+j ----
    const float* wc = dww + c * 121;
    f16x8 afrag[11];
    #pragma unroll
    for (int dy = 0; dy < 11; ++dy) {
        f16x8 a;
        #pragma unroll
        for (int j = 0; j < 8; ++j) {
            int d = kg8 + j - lm - 3;
            int dcl = min(max(d, 0), 10);
            float wv = wc[dy * 11 + dcl];
            a[j] = (__fp16)((d == dcl) ? wv : 0.f);
        }
        afrag[dy] = a;
    }

    f16x2v bias2; bias2.x = (__fp16)ba1; bias2.y = (__fp16)ba1;

    // ---- preload P pairs (+bias) and pair offsets ----
    int offs[NU2];
    u32 preg[NU2];
    const u32* Pc = Ph + (size_t)(i * CC + c) * HWP;
    #pragma unroll
    for (int u = 0; u < NU2; ++u) {
        int d = t + u * 256;
        int row = d / (GPITCH / 2);
        int cp  = d - row * (GPITCH / 2);
        int gy = y0 + row - 5;
        int gx = x0 + 2 * cp - 8;
        bool inb = (d < GDW) && (gy >= 0) && (gy < HH) && (gx >= 0) && (gx < WW);
        offs[u] = inb ? (gy * (WW / 2) + (gx >> 1)) : -1;
        u32 p = 0u;
        if (inb) {
            f16x2v ph = __builtin_bit_cast(f16x2v, Pc[offs[u]]) + bias2;
            p = __builtin_bit_cast(u32, ph);
        }
        preg[u] = p;
    }

    // ---- per-lane output coordinates ----
    const int oy  = y0 + ty * 16 + lm;        // image row
    const int obx = x0 + kg * 4;              // x base; tile tx adds 16*tx
    const int obase = oy * WW + obx;

    f32x4 sacc[4];
    #pragma unroll
    for (int tx = 0; tx < 4; ++tx) sacc[tx] = (f32x4){0.f, 0.f, 0.f, 0.f};

    // prefetch Q pairs for k=0
    u32 qreg[NU2];
    {
        const u32* Qc = Qh + (size_t)(0 * CC + c) * HWP;
        #pragma unroll
        for (int u = 0; u < NU2; ++u)
            qreg[u] = (offs[u] >= 0) ? Qc[offs[u]] : 0u;
    }

    const int rowb = (ty * 16 + lm) * GPITCH + kg8;   // half-index base for B reads

    #pragma unroll 1
    for (int k = 0; k < NAG; ++k) {
        // ---- prefetch this k's W values (consumed after the conv)
        const float* Wc = W + (size_t)(k * CC + c) * HWT + obase;
        f32x4 wk[4];
        #pragma unroll
        for (int tx = 0; tx < 4; ++tx)
            wk[tx] = *(const f32x4*)(Wc + 16 * tx);

        // ---- gelu phase: GT = gelu(P + Q + b) as f16 pairs (data already in regs)
        #pragma unroll
        for (int u = 0; u < NU2; ++u) {
            int d = t + u * 256;
            if (u < NU2 - 1 || d < GDW) {
                f16x2v s = __builtin_bit_cast(f16x2v, preg[u]) +
                           __builtin_bit_cast(f16x2v, qreg[u]);
                float g0 = gelu_fast((float)s.x);
                float g1 = gelu_fast((float)s.y);
                GT32[d] = __builtin_bit_cast(u32, __builtin_amdgcn_cvt_pkrtz(g0, g1));
            }
        }
        __syncthreads();

        // ---- prefetch next k's Q (latency hidden under the conv)
        if (k + 1 < NAG) {
            const u32* Qc = Qh + (size_t)((k + 1) * CC + c) * HWP;
            #pragma unroll
            for (int u = 0; u < NU2; ++u)
                qreg[u] = (offs[u] >= 0) ? Qc[offs[u]] : 0u;
        }

        // ---- conv: per tile tx, 11 dy -> 11 (ds_read_b128 + MFMA)
        #pragma unroll
        for (int tx = 0; tx < 4; ++tx) {
            f32x4 acc = (f32x4){0.f, 0.f, 0.f, 0.f};
            #pragma unroll
            for (int dy = 0; dy < 11; ++dy) {
                f16x8 b = *(const f16x8*)(GTh + rowb + dy * GPITCH + 16 * tx);
                acc = __builtin_amdgcn_mfma_f32_16x16x32_f16(afrag[dy], b, acc, 0, 0, 0);
            }
            sacc[tx] += (acc + bdw) * wk[tx];
        }
        __syncthreads();  // conv reads done before next k's writes
    }

    // ---- epilogue: multiply by (1 - conf_norm_i), store
    const float mn = __uint_as_float(mm[i]);
    const float mx = __uint_as_float(mm[i + NAG]);
    const float inv = 1.f / (mx - mn);
    const float* cfi = conf + i * HWT + obase;
    float* Sc = S + (size_t)(i * CC + c) * HWT + obase;
    #pragma unroll
    for (int tx = 0; tx < 4; ++tx) {
        f32x4 cv = *(const f32x4*)(cfi + 16 * tx);
        f32x4 r = sacc[tx] * (1.f - (cv - mn) * inv);
        *(f32x4*)(Sc + 16 * tx) = r;
    }
}

// ---------------- epilogue: out = raw + projW * S + 6*pb (S aliases out) ----------------
__global__ __launch_bounds__(512) void k_out(
    float* so,
    const float* __restrict__ raw,
    const float* __restrict__ pw, const float* __restrict__ pb)
{
    const int n = blockIdx.y;
    const int og = __builtin_amdgcn_readfirstlane(threadIdx.x >> 6);
    const int pg = threadIdx.x & 63;
    const int px = blockIdx.x * 256 + pg * 4;

    const float* xb = so + (size_t)(n * CC) * HWT + px;

    float acc[8][4];
    #pragma unroll
    for (int j = 0; j < 8; ++j)
        for (int q = 0; q < 4; ++q) acc[j][q] = 0.f;

    #pragma unroll 4
    for (int c = 0; c < CC; ++c) {
        float4 x = *(const float4*)(xb + (size_t)c * HWT);
        #pragma unroll
        for (int j = 0; j < 8; ++j) {
            float w = pw[(og * 8 + j) * CC + c];
            acc[j][0] = fmaf(w, x.x, acc[j][0]);
            acc[j][1] = fmaf(w, x.y, acc[j][1]);
            acc[j][2] = fmaf(w, x.z, acc[j][2]);
            acc[j][3] = fmaf(w, x.w, acc[j][3]);
        }
    }

    __syncthreads();

    #pragma unroll
    for (int j = 0; j < 8; ++j) {
        int o = og * 8 + j;
        float bias = (float)NAG * pb[o];
        float4 r = *(const float4*)(raw + (size_t)(n * CC + o) * HWT + px);
        float4 w = make_float4(r.x + acc[j][0] + bias, r.y + acc[j][1] + bias,
                               r.z + acc[j][2] + bias, r.w + acc[j][3] + bias);
        *(float4*)(so + (size_t)(n * CC + o) * HWT + px) = w;
    }
}

extern "C" void kernel_launch(void* const* d_in, const int* in_sizes, int n_in,
                              void* d_out, int out_size, void* d_ws, size_t ws_size,
                              hipStream_t stream)
{
    (void)in_sizes; (void)n_in; (void)out_size; (void)ws_size;

    const float* raw   = (const float*)d_in[0];
    const float* pw_w1 = (const float*)d_in[1];
    const float* pw_b1 = (const float*)d_in[2];
    const float* bng   = (const float*)d_in[3];
    const float* bnb   = (const float*)d_in[4];
    const float* bnm   = (const float*)d_in[5];
    const float* bnv   = (const float*)d_in[6];
    const float* pw_w2 = (const float*)d_in[7];
    const float* pw_b2 = (const float*)d_in[8];
    const float* a1w   = (const float*)d_in[9];
    const float* a1b   = (const float*)d_in[10];
    const float* dww   = (const float*)d_in[11];
    const float* dwb   = (const float*)d_in[12];
    const float* vw    = (const float*)d_in[13];
    const float* vb    = (const float*)d_in[14];
    const float* pjw   = (const float*)d_in[15];
    const float* pjb   = (const float*)d_in[16];

    float* ws   = (float*)d_ws;
    float* conf = ws;                                   // 6*16384 f32
    u32*   mm   = (u32*)(ws + NAG * HWT);               // 16 u32
    u32*   Ph   = (u32*)(ws + NAG * HWT + 16);          // 6*64*8192 u32
    u32*   Qh   = Ph + (size_t)NAG * CC * HWP;          // 6*64*8192 u32
    float* W    = (float*)(Qh + (size_t)NAG * CC * HWP);// 6*64*16384 f32
    float* S    = (float*)d_out;                        // S aliases output

    k_init<<<dim3(1), dim3(64), 0, stream>>>(mm);
    k_conf<<<dim3(HWT / 256, NAG), dim3(256), 0, stream>>>(raw, pw_w1, pw_b1, bng, bnb,
                                                           bnm, bnv, pw_w2, pw_b2, conf, mm);
    k_pqv<<<dim3(HWT / 256, NAG, 3), dim3(512), 0, stream>>>(raw, a1w, vw, vb, conf, mm,
                                                             Ph, Qh, W);
    k_main<<<dim3(4, CC, NAG), dim3(256), 0, stream>>>(Ph, Qh, W, conf, mm, a1b, dww, dwb, S);
    k_out<<<dim3(HWT / 256, NAG), dim3(512), 0, stream>>>(S, raw, pjw, pjb);
}

// Round 8
// 119.626 us; speedup vs baseline: 3.6844x; 1.1318x over previous
//
#include <hip/hip_runtime.h>
#include <math.h>

#define NAG 6
#define CC  64
#define HH  128
#define WW  128
#define HWT 16384
#define HWP 8192             // packed f16 pairs per (agent,channel) plane
#define BN_EPS 1e-5f
#define WFRAG_PJ_OFF (24 * 64 * 8)   // halves: P/Q/W slots first, then proj slots

typedef unsigned int u32;
typedef __fp16 f16x2v __attribute__((ext_vector_type(2)));
typedef __fp16 f16x8  __attribute__((ext_vector_type(8)));
typedef float  f32x4  __attribute__((ext_vector_type(4)));

// branch-free tanh-form gelu, exp2-folded
__device__ __forceinline__ float gelu_fast(float x) {
    float s = x * x;
    float m = fmaf(s, -0.10294535f, -2.30226045f);   // -(2*0.79788456*log2e)*(1+0.044715 s)
    float e = __builtin_amdgcn_exp2f(x * m);          // e^{-2a}
    return x * __builtin_amdgcn_rcpf(1.0f + e);       // x * sigmoid(2a)
}

// ---------------- init min/max slots ----------------
__global__ void k_init(u32* __restrict__ mm) {
    int t = threadIdx.x;
    if (t < NAG) mm[t] = 0x7F800000u;        // +inf (min slots)
    else if (t < 2 * NAG) mm[t] = 0u;        // 0    (max slots; h2 >= 0)
}

// ---------------- prepack weights into MFMA B-fragment order (f16) ----------------
// slot s (0..23): P(ot 0..3)/Q(4..7)/W(8..11) x kf; slot 24..31: proj (ot 0..3) x kf.
// Layout: wfrag[(slot*64 + lane)*8 + j] = w[o = otl*16 + (lane&15)][ch = kf*32 + (lane>>4)*8 + j]
__global__ __launch_bounds__(256) void k_wprep(
    const float* __restrict__ a1w, const float* __restrict__ vw,
    const float* __restrict__ pjw, __fp16* __restrict__ wfrag)
{
    int t = blockIdx.x * 256 + threadIdx.x;
    if (t >= 32 * 64) return;
    int lane = t & 63;
    int slot = t >> 6;
    bool pj = slot >= 24;
    int s = pj ? slot - 24 : slot;
    int ot = s >> 1, kf = s & 1;
    int o  = (pj ? ot : (ot & 3)) * 16 + (lane & 15);
    int ch = kf * 32 + (lane >> 4) * 8;
    const float* src;
    if (pj)          src = pjw + o * CC + ch;
    else if (ot < 4) src = a1w + o * 2 * CC + ch;            // A1 (P)
    else if (ot < 8) src = a1w + o * 2 * CC + CC + ch;       // A2 (Q)
    else             src = vw  + o * CC + ch;                // V  (W)
    __fp16* dst = wfrag + ((size_t)slot * 64 + lane) * 8;
    #pragma unroll
    for (int j = 0; j < 8; ++j) dst[j] = (__fp16)src[j];
}

// ---------------- confidence maps (pre-normalization) + per-agent min/max ----------------
__global__ __launch_bounds__(256) void k_conf(
    const float* __restrict__ raw,
    const float* __restrict__ w1, const float* __restrict__ b1,
    const float* __restrict__ gamma, const float* __restrict__ beta,
    const float* __restrict__ mean, const float* __restrict__ var,
    const float* __restrict__ w2, const float* __restrict__ b2,
    float* __restrict__ conf, u32* __restrict__ mm)
{
    const int n = blockIdx.y;
    const int p = blockIdx.x * 256 + threadIdx.x;
    const float* x = raw + (size_t)(n * CC) * HWT + p;

    float a[4] = {0.f, 0.f, 0.f, 0.f};
    #pragma unroll 8
    for (int c = 0; c < CC; ++c) {
        float v = x[c * HWT];
        a[0] = fmaf(w1[0 * CC + c], v, a[0]);
        a[1] = fmaf(w1[1 * CC + c], v, a[1]);
        a[2] = fmaf(w1[2 * CC + c], v, a[2]);
        a[3] = fmaf(w1[3 * CC + c], v, a[3]);
    }
    float h2 = b2[0];
    #pragma unroll
    for (int o = 0; o < 4; ++o) {
        float sc = gamma[o] * rsqrtf(var[o] + BN_EPS);
        float hb = (a[o] + b1[o] - mean[o]) * sc + beta[o];
        hb = fmaxf(hb, 0.f);
        h2 = fmaf(w2[o], hb, h2);
    }
    h2 = fmaxf(h2, 0.f);
    conf[n * HWT + p] = h2;

    float mn = h2, mx = h2;
    #pragma unroll
    for (int off = 32; off > 0; off >>= 1) {
        mn = fminf(mn, __shfl_xor(mn, off, 64));
        mx = fmaxf(mx, __shfl_xor(mx, off, 64));
    }
    __shared__ float smn[4], smx[4];
    int wid = threadIdx.x >> 6, lane = threadIdx.x & 63;
    if (lane == 0) { smn[wid] = mn; smx[wid] = mx; }
    __syncthreads();
    if (threadIdx.x == 0) {
        mn = fminf(fminf(smn[0], smn[1]), fminf(smn[2], smn[3]));
        mx = fmaxf(fmaxf(smx[0], smx[1]), fmaxf(smx[2], smx[3]));
        atomicMin(&mm[n], __float_as_uint(mn));
        atomicMax(&mm[n + NAG], __float_as_uint(mx));
    }
}

// ---------------- MFMA GEMM: P/Q (f16) + W (f32) in one pass over raw ----------------
// Swapped orientation: A-slot = raw [px][ch], B-slot = weights [ch][o], D = [px][o].
// Block = 128 px, 4 waves x 32 px (2 m-tiles). 12 o-tiles: 0-3 P, 4-7 Q, 8-11 W.
__global__ __launch_bounds__(256) void k_pqv(
    const float* __restrict__ raw, const __fp16* __restrict__ wfrag,
    const float* __restrict__ vb, const float* __restrict__ conf,
    const u32* __restrict__ mm,
    u32* __restrict__ Ph, u32* __restrict__ Qh, float* __restrict__ W)
{
    const int n   = blockIdx.y;
    const int px0 = blockIdx.x * 128;
    const int t = threadIdx.x, lane = t & 63, wv = t >> 6;
    const int lm = lane & 15, kg = lane >> 4;
    const int pxw = px0 + wv * 32;
    const int pxl = pxw + lm;           // A-frag px (+ mt*16)
    const int pxs = pxw + kg * 4;       // store px base (+ mt*16)

    const float* rawn = raw + (size_t)n * CC * HWT;

    // A-fragments: raw -> f16, [mt][kf]
    f16x8 afr[2][2];
    #pragma unroll
    for (int mt = 0; mt < 2; ++mt) {
        #pragma unroll
        for (int kf = 0; kf < 2; ++kf) {
            const float* base = rawn + (size_t)(kf * 32 + kg * 8) * HWT + pxl + mt * 16;
            f16x8 a;
            #pragma unroll
            for (int p = 0; p < 4; ++p) {
                f16x2v h = __builtin_amdgcn_cvt_pkrtz(base[(2 * p) * HWT],
                                                      base[(2 * p + 1) * HWT]);
                a[2 * p] = h.x; a[2 * p + 1] = h.y;
            }
            afr[mt][kf] = a;
        }
    }

    // conf_norm for W stores (per mt; same for all o)
    const float mn = __uint_as_float(mm[n]);
    const float mx = __uint_as_float(mm[n + NAG]);
    const float inv = 1.f / (mx - mn);
    f32x4 cn[2];
    #pragma unroll
    for (int mt = 0; mt < 2; ++mt) {
        f32x4 cv = *(const f32x4*)(conf + n * HWT + pxs + mt * 16);
        cn[mt] = (cv - mn) * inv;
    }

    #pragma unroll
    for (int ot = 0; ot < 12; ++ot) {
        f16x8 b0 = *(const f16x8*)(wfrag + ((size_t)(ot * 2 + 0) * 64 + lane) * 8);
        f16x8 b1 = *(const f16x8*)(wfrag + ((size_t)(ot * 2 + 1) * 64 + lane) * 8);
        const int o = (ot & 3) * 16 + lm;
        #pragma unroll
        for (int mt = 0; mt < 2; ++mt) {
            f32x4 acc = (f32x4){0.f, 0.f, 0.f, 0.f};
            acc = __builtin_amdgcn_mfma_f32_16x16x32_f16(afr[mt][0], b0, acc, 0, 0, 0);
            acc = __builtin_amdgcn_mfma_f32_16x16x32_f16(afr[mt][1], b1, acc, 0, 0, 0);
            const int pxb = pxs + mt * 16;
            if (ot < 8) {
                u32* plane = (ot < 4 ? Ph : Qh) + (size_t)(n * CC + o) * HWP + (pxb >> 1);
                f16x2v h0 = __builtin_amdgcn_cvt_pkrtz(acc[0], acc[1]);
                f16x2v h1 = __builtin_amdgcn_cvt_pkrtz(acc[2], acc[3]);
                *(uint2*)plane = make_uint2(__builtin_bit_cast(u32, h0),
                                            __builtin_bit_cast(u32, h1));
            } else {
                f32x4 r = (acc + vb[o]) * cn[mt];
                *(f32x4*)(W + (size_t)(n * CC + o) * HWT + pxb) = r;
            }
        }
    }
}

// ---------------- main: S[i,c] = sum_k dwconv11(gelu(P_i+Q_k+b)) * W_k, conv via MFMA ----------------
#define GPITCH 88
#define GROWS  74
#define GDW    (GROWS * GPITCH / 2)   // 3256 dwords
#define NU2    13

__global__ __launch_bounds__(256, 3) void k_main(
    const u32* __restrict__ Ph, const u32* __restrict__ Qh,
    const float* __restrict__ W, const float* __restrict__ conf,
    const u32* __restrict__ mm,
    const float* __restrict__ a1b, const float* __restrict__ dww,
    const float* __restrict__ dwb, float* __restrict__ S)
{
    const int tile = blockIdx.x;              // 0..3 image quadrant
    const int c    = blockIdx.y;              // 0..63
    const int i    = blockIdx.z;              // 0..5
    const int y0 = (tile >> 1) * 64;
    const int x0 = (tile & 1) * 64;
    const int t    = threadIdx.x;
    const int lane = t & 63;
    const int ty   = t >> 6;                  // wave id = output row-tile
    const int lm   = lane & 15;
    const int kg   = lane >> 4;               // 0..3
    const int kg8  = kg * 8;

    __shared__ __align__(16) u32 GT32[GDW];
    const __fp16* GTh = (const __fp16*)GT32;

    const float bdw = dwb[c];
    const float ba1 = a1b[c];

    // A fragments: Toeplitz band A[m][k] = w[dy][k-m-3]
    const float* wc = dww + c * 121;
    f16x8 afrag[11];
    #pragma unroll
    for (int dy = 0; dy < 11; ++dy) {
        f16x8 a;
        #pragma unroll
        for (int j = 0; j < 8; ++j) {
            int d = kg8 + j - lm - 3;
            int dcl = min(max(d, 0), 10);
            float wv = wc[dy * 11 + dcl];
            a[j] = (__fp16)((d == dcl) ? wv : 0.f);
        }
        afrag[dy] = a;
    }

    f16x2v bias2; bias2.x = (__fp16)ba1; bias2.y = (__fp16)ba1;

    // preload P pairs (+bias) and pair offsets
    int offs[NU2];
    u32 preg[NU2];
    const u32* Pc = Ph + (size_t)(i * CC + c) * HWP;
    #pragma unroll
    for (int u = 0; u < NU2; ++u) {
        int d = t + u * 256;
        int row = d / (GPITCH / 2);
        int cp  = d - row * (GPITCH / 2);
        int gy = y0 + row - 5;
        int gx = x0 + 2 * cp - 8;
        bool inb = (d < GDW) && (gy >= 0) && (gy < HH) && (gx >= 0) && (gx < WW);
        offs[u] = inb ? (gy * (WW / 2) + (gx >> 1)) : -1;
        u32 p = 0u;
        if (inb) {
            f16x2v ph = __builtin_bit_cast(f16x2v, Pc[offs[u]]) + bias2;
            p = __builtin_bit_cast(u32, ph);
        }
        preg[u] = p;
    }

    const int oy  = y0 + ty * 16 + lm;
    const int obx = x0 + kg * 4;
    const int obase = oy * WW + obx;

    f32x4 sacc[4];
    #pragma unroll
    for (int tx = 0; tx < 4; ++tx) sacc[tx] = (f32x4){0.f, 0.f, 0.f, 0.f};

    u32 qreg[NU2];
    {
        const u32* Qc = Qh + (size_t)(0 * CC + c) * HWP;
        #pragma unroll
        for (int u = 0; u < NU2; ++u)
            qreg[u] = (offs[u] >= 0) ? Qc[offs[u]] : 0u;
    }

    const int rowb = (ty * 16 + lm) * GPITCH + kg8;

    #pragma unroll 1
    for (int k = 0; k < NAG; ++k) {
        const float* Wc = W + (size_t)(k * CC + c) * HWT + obase;
        f32x4 wk[4];
        #pragma unroll
        for (int tx = 0; tx < 4; ++tx)
            wk[tx] = *(const f32x4*)(Wc + 16 * tx);

        #pragma unroll
        for (int u = 0; u < NU2; ++u) {
            int d = t + u * 256;
            if (u < NU2 - 1 || d < GDW) {
                f16x2v s = __builtin_bit_cast(f16x2v, preg[u]) +
                           __builtin_bit_cast(f16x2v, qreg[u]);
                float g0 = gelu_fast((float)s.x);
                float g1 = gelu_fast((float)s.y);
                GT32[d] = __builtin_bit_cast(u32, __builtin_amdgcn_cvt_pkrtz(g0, g1));
            }
        }
        __syncthreads();

        if (k + 1 < NAG) {
            const u32* Qc = Qh + (size_t)((k + 1) * CC + c) * HWP;
            #pragma unroll
            for (int u = 0; u < NU2; ++u)
                qreg[u] = (offs[u] >= 0) ? Qc[offs[u]] : 0u;
        }

        #pragma unroll
        for (int tx = 0; tx < 4; ++tx) {
            f32x4 acc = (f32x4){0.f, 0.f, 0.f, 0.f};
            #pragma unroll
            for (int dy = 0; dy < 11; ++dy) {
                f16x8 b = *(const f16x8*)(GTh + rowb + dy * GPITCH + 16 * tx);
                acc = __builtin_amdgcn_mfma_f32_16x16x32_f16(afrag[dy], b, acc, 0, 0, 0);
            }
            sacc[tx] += (acc + bdw) * wk[tx];
        }
        __syncthreads();
    }

    const float mn = __uint_as_float(mm[i]);
    const float mx = __uint_as_float(mm[i + NAG]);
    const float inv = 1.f / (mx - mn);
    const float* cfi = conf + i * HWT + obase;
    float* Sc = S + (size_t)(i * CC + c) * HWT + obase;
    #pragma unroll
    for (int tx = 0; tx < 4; ++tx) {
        f32x4 cv = *(const f32x4*)(cfi + 16 * tx);
        f32x4 r = sacc[tx] * (1.f - (cv - mn) * inv);
        *(f32x4*)(Sc + 16 * tx) = r;
    }
}

// ---------------- MFMA epilogue: out = raw + projW * S + 6*pb (S aliases out) ----------------
// Per wave: all S reads (A-frags, full K) complete before any store; waves own disjoint px.
__global__ __launch_bounds__(256) void k_out(
    float* so, const float* __restrict__ raw,
    const __fp16* __restrict__ wfrag, const float* __restrict__ pb)
{
    const int n   = blockIdx.y;
    const int px0 = blockIdx.x * 128;
    const int t = threadIdx.x, lane = t & 63, wv = t >> 6;
    const int lm = lane & 15, kg = lane >> 4;
    const int pxw = px0 + wv * 32;
    const int pxl = pxw + lm;
    const int pxs = pxw + kg * 4;

    const float* Sn = so + (size_t)n * CC * HWT;

    f16x8 afr[2][2];
    #pragma unroll
    for (int mt = 0; mt < 2; ++mt) {
        #pragma unroll
        for (int kf = 0; kf < 2; ++kf) {
            const float* base = Sn + (size_t)(kf * 32 + kg * 8) * HWT + pxl + mt * 16;
            f16x8 a;
            #pragma unroll
            for (int p = 0; p < 4; ++p) {
                f16x2v h = __builtin_amdgcn_cvt_pkrtz(base[(2 * p) * HWT],
                                                      base[(2 * p + 1) * HWT]);
                a[2 * p] = h.x; a[2 * p + 1] = h.y;
            }
            afr[mt][kf] = a;
        }
    }

    #pragma unroll
    for (int ot = 0; ot < 4; ++ot) {
        f16x8 b0 = *(const f16x8*)(wfrag + WFRAG_PJ_OFF +
                                   ((size_t)(ot * 2 + 0) * 64 + lane) * 8);
        f16x8 b1 = *(const f16x8*)(wfrag + WFRAG_PJ_OFF +
                                   ((size_t)(ot * 2 + 1) * 64 + lane) * 8);
        const int o = ot * 16 + lm;
        const float bias = (float)NAG * pb[o];
        #pragma unroll
        for (int mt = 0; mt < 2; ++mt) {
            f32x4 acc = (f32x4){0.f, 0.f, 0.f, 0.f};
            acc = __builtin_amdgcn_mfma_f32_16x16x32_f16(afr[mt][0], b0, acc, 0, 0, 0);
            acc = __builtin_amdgcn_mfma_f32_16x16x32_f16(afr[mt][1], b1, acc, 0, 0, 0);
            const int pxb = pxs + mt * 16;
            f32x4 r = *(const f32x4*)(raw + (size_t)(n * CC + o) * HWT + pxb);
            f32x4 out = r + acc + bias;
            *(f32x4*)(so + (size_t)(n * CC + o) * HWT + pxb) = out;
        }
    }
}

extern "C" void kernel_launch(void* const* d_in, const int* in_sizes, int n_in,
                              void* d_out, int out_size, void* d_ws, size_t ws_size,
                              hipStream_t stream)
{
    (void)in_sizes; (void)n_in; (void)out_size; (void)ws_size;

    const float* raw   = (const float*)d_in[0];
    const float* pw_w1 = (const float*)d_in[1];
    const float* pw_b1 = (const float*)d_in[2];
    const float* bng   = (const float*)d_in[3];
    const float* bnb   = (const float*)d_in[4];
    const float* bnm   = (const float*)d_in[5];
    const float* bnv   = (const float*)d_in[6];
    const float* pw_w2 = (const float*)d_in[7];
    const float* pw_b2 = (const float*)d_in[8];
    const float* a1w   = (const float*)d_in[9];
    const float* a1b   = (const float*)d_in[10];
    const float* dww   = (const float*)d_in[11];
    const float* dwb   = (const float*)d_in[12];
    const float* vw    = (const float*)d_in[13];
    const float* vb    = (const float*)d_in[14];
    const float* pjw   = (const float*)d_in[15];
    const float* pjb   = (const float*)d_in[16];

    float* ws   = (float*)d_ws;
    float* conf = ws;                                    // 6*16384 f32
    u32*   mm   = (u32*)(ws + NAG * HWT);                // 16 u32
    u32*   Ph   = (u32*)(ws + NAG * HWT + 16);           // 6*64*8192 u32
    u32*   Qh   = Ph + (size_t)NAG * CC * HWP;           // 6*64*8192 u32
    float* W    = (float*)(Qh + (size_t)NAG * CC * HWP); // 6*64*16384 f32
    __fp16* wfrag = (__fp16*)(W + (size_t)NAG * CC * HWT); // 16384 halves (32 KB)
    float* S    = (float*)d_out;                         // S aliases output

    k_init<<<dim3(1), dim3(64), 0, stream>>>(mm);
    k_wprep<<<dim3(8), dim3(256), 0, stream>>>(a1w, vw, pjw, wfrag);
    k_conf<<<dim3(HWT / 256, NAG), dim3(256), 0, stream>>>(raw, pw_w1, pw_b1, bng, bnb,
                                                           bnm, bnv, pw_w2, pw_b2, conf, mm);
    k_pqv<<<dim3(HWT / 128, NAG), dim3(256), 0, stream>>>(raw, wfrag, vb, conf, mm,
                                                          Ph, Qh, W);
    k_main<<<dim3(4, CC, NAG), dim3(256), 0, stream>>>(Ph, Qh, W, conf, mm, a1b, dww, dwb, S);
    k_out<<<dim3(HWT / 128, NAG), dim3(256), 0, stream>>>(S, raw, wfrag, pjb);
}